// Round 10
// baseline (216.109 us; speedup 1.0000x reference)
//
#include <hip/hip_runtime.h>
#include <stdint.h>

typedef uint32_t u32;
typedef short s16x8 __attribute__((ext_vector_type(8)));
typedef float f32x16 __attribute__((ext_vector_type(16)));
typedef u32 u32x2 __attribute__((ext_vector_type(2)));
typedef u32 u32x4 __attribute__((ext_vector_type(4)));

#define NPIX   262144
#define HD     256

// ---------------- fused geometry (r8 partition) ----------------
// 128 px per block, 512 threads (8 waves, one 32-feature block each),
// act-only LDS = 64 KB -> 2 blocks/CU -> 4 waves/SIMD.
#define FTHR      512
#define PXB       128
#define NBLK      (NPIX / PXB)        // 2048
#define ACT_LDS   65536

// ---------------- weight blob (d_ws): per-lane MFMA A-fragment images ----------------
// hidden tile = [kk 16][fb 8][lane 64] x 16B = 128 KB; frag(lane) holds
// W[k = kk*16 + (lane>>5)*8 + j][f = fb*32 + (lane&31)], j=0..7, bf16.
#define B0_OFF  0u           // w0: [kk 4][fb 8][lane] = 32 KB (K=54 padded to 64)
#define B1_OFF  32768u       // w1: 4 tiles
#define B2_OFF  557056u      // w2: 16 tiles
#define B3_OFF  2654208u     // w3: 64 tiles
#define B4_OFF  11042816u    // w4: 256 tiles
#define BH_OFF  44597248u    // head: [kk 16][lane 64] = 16 KB (3 ch padded to 32)
#define BLOB_TOTAL 44613632u
#define F_W1 2048u
#define F_W2 34816u
#define F_W3 165888u
#define F_W4 690176u
#define F_WH 2787328u
#define F_END 2788352u

// fallback (r2-style) LDS layout
#define ACT_BYTES  131072
#define WBUF_BYTES 16384
#define FB_LDS     (ACT_BYTES + 2 * WBUF_BYTES)

__device__ __forceinline__ u32 bfpair(float a, float b) {   // RTNE pack (bit ops, proven)
    u32 ua = __builtin_bit_cast(u32, a);
    u32 ub = __builtin_bit_cast(u32, b);
    ua = (ua + 0x7FFFu + ((ua >> 16) & 1u)) >> 16;
    ub = (ub + 0x7FFFu + ((ub >> 16) & 1u)) >> 16;
    return ua | (ub << 16);
}
// act: row stride 512B; XOR-swizzle byte bits 4-8 by row&31 (bijective, 32-slot spread)
__device__ __forceinline__ u32 act_off(int row, int colByte) {
    return (u32)((row << 9) + (colByte ^ ((row & 31) << 4)));
}
// fallback wbuf: col stride 64B, swizzle bits 4-5 by (col>>1)&3
__device__ __forceinline__ u32 w_off32(int col, int kByte) {
    return (u32)((col << 6) + (kByte ^ (((col >> 1) & 3) << 4)));
}

// =================== pre-pass: f32 weights -> per-lane fragment blob (r6-identical) ===========
extern "C" __global__ __launch_bounds__(256)
void loe_prepass(const float* __restrict__ w0, const float* __restrict__ w1,
                 const float* __restrict__ w2, const float* __restrict__ w3,
                 const float* __restrict__ w4, const float* __restrict__ wl,
                 char* __restrict__ ws)
{
    const u32 f = blockIdx.x * 256 + threadIdx.x;   // one 16B fragment chunk
    if (f >= F_END) return;
    float v[8];
    char* dst;
    if (f < F_W1) {                                   // ---- w0 ----
        const u32 kk = f >> 9, fb = (f >> 6) & 7, lane = f & 63;
        const u32 l31 = lane & 31, lhi = lane >> 5;
        const u32 k0 = kk * 16 + lhi * 8, col = fb * 32 + l31;
        #pragma unroll
        for (int j = 0; j < 8; ++j)
            v[j] = (k0 + j < 54) ? w0[(k0 + j) * HD + col] : 0.0f;
        dst = ws + B0_OFF + (size_t)f * 16;
    } else if (f < F_WH) {                            // ---- hidden layers ----
        const float* W; size_t boff; u32 fl;
        if (f < F_W2)      { W = w1; boff = B1_OFF; fl = f - F_W1; }
        else if (f < F_W3) { W = w2; boff = B2_OFF; fl = f - F_W2; }
        else if (f < F_W4) { W = w3; boff = B3_OFF; fl = f - F_W3; }
        else               { W = w4; boff = B4_OFF; fl = f - F_W4; }
        const u32 t = fl >> 13, c = fl & 8191;
        const u32 kk = c >> 9, fb = (c >> 6) & 7, lane = c & 63;
        const u32 l31 = lane & 31, lhi = lane >> 5;
        const u32 k0 = kk * 16 + lhi * 8, col = fb * 32 + l31;
        const float* src = W + (size_t)t * 65536 + (size_t)k0 * HD + col;
        #pragma unroll
        for (int j = 0; j < 8; ++j) v[j] = src[(size_t)j * HD];
        dst = ws + boff + (size_t)fl * 16;
    } else {                                          // ---- head ----
        const u32 fl = f - F_WH;
        const u32 kk = fl >> 6, lane = fl & 63;
        const u32 l31 = lane & 31, lhi = lane >> 5;
        const u32 k0 = kk * 16 + lhi * 8;
        #pragma unroll
        for (int j = 0; j < 8; ++j)
            v[j] = (l31 < 3) ? wl[l31 * HD + k0 + j] : 0.0f;
        dst = ws + BH_OFF + (size_t)fl * 16;
    }
    u32x4 pk;
    pk.x = bfpair(v[0], v[1]); pk.y = bfpair(v[2], v[3]);
    pk.z = bfpair(v[4], v[5]); pk.w = bfpair(v[6], v[7]);
    *reinterpret_cast<u32x4*>(dst) = pk;
}

// ====== fused MLP: 8 waves, depth-4 W prefetch, per-wave K-chunk rotation (de-convoy) ======
extern "C" __global__ __launch_bounds__(FTHR, 4)
void loe_fused_pre(const float* __restrict__ coords,
                   const float* __restrict__ b0, const float* __restrict__ b1,
                   const float* __restrict__ b2, const float* __restrict__ b3,
                   const float* __restrict__ b4, const float* __restrict__ bl,
                   const char* __restrict__ blob,
                   float* __restrict__ out)
{
    extern __shared__ char lds[];

    const int tid  = threadIdx.x;
    const int lane = tid & 63;
    const int wv   = tid >> 6;      // wave 0..7 = 32-feature block (head: px group for wv<4)
    const int l31  = lane & 31;
    const int lhi  = lane >> 5;

    const int bid  = (int)blockIdx.x;
    const int pb   = ((bid & 7) << 8) | (bid >> 3);   // bijective XCD swizzle (2048 = 8*256)
    const int pix0 = pb << 7;

    // per-wave chunk-order rotation offsets: K-sum order is associativity-neutral
    const int off4  = wv & 3;          // layer-0 (KK=4)
    const int off16 = (wv & 3) * 4;    // hidden layers (KK=16)

    const size_t fragoff = (size_t)wv * 1024 + (size_t)lane * 16;
    auto ldfrag = [&](const char* base, int chunk) -> u32x4 {
        return *reinterpret_cast<const u32x4*>(base + (size_t)chunk * 8192 + fragoff);
    };

    const char* b0p = blob + B0_OFF;
    const char* b1p = blob + B1_OFF + (size_t)(pb >> 9) * 131072;
    const char* b2p = blob + B2_OFF + (size_t)(pb >> 7) * 131072;
    const char* b3p = blob + B3_OFF + (size_t)(pb >> 5) * 131072;
    const char* b4p = blob + B4_OFF + (size_t)(pb >> 3) * 131072;
    const char* bHp = blob + BH_OFF;

    // depth-4 W pipeline registers; layer-0 prologue (rotated) issued BEFORE the PE trig burst
    u32x4 wr0 = ldfrag(b0p, (0 + off4) & 3), wr1 = ldfrag(b0p, (1 + off4) & 3),
          wr2 = ldfrag(b0p, (2 + off4) & 3), wr3 = ldfrag(b0p, (3 + off4) & 3);

    // ---------------- positional encoding -> act[128 px][64 cols] ----------------
    {
        const int p = tid >> 2;         // 4 threads per pixel
        const int h = tid & 3;          // 16 cols each
        const float2 c2 = reinterpret_cast<const float2*>(coords)[pix0 + p];
        const float cf[2] = {c2.x, c2.y};
        #pragma unroll
        for (int u = 0; u < 16; u += 2) {
            float v[2];
            #pragma unroll
            for (int q = 0; q < 2; ++q) {
                const int c = h * 16 + u + q;
                float val;
                if (c < 2) val = cf[c];
                else if (c - 2 >= 52) val = 0.0f;
                else {
                    const int e = c - 2;
                    const float a = cf[(e >> 1) & 1] * (float)(1 << (e >> 2));  // exact pow2 scale
                    val = (e & 1) ? cospif(a) : sinpif(a);     // proven path
                }
                v[q] = val;
            }
            *reinterpret_cast<u32*>(lds + act_off(p, (h * 16 + u) * 2)) = bfpair(v[0], v[1]);
        }
    }

    f32x16 acc[4];                    // acc[px-block]; D row=feature(32 of wave), col=px
    const u32 swz = (u32)(l31 << 4);
    u32 abase[4];
    #pragma unroll
    for (int pt = 0; pt < 4; ++pt) abase[pt] = (u32)((pt * 32 + l31) << 9);

    auto init_acc = [&](const float* Bias) {
        #pragma unroll
        for (int q = 0; q < 4; ++q) {
            const float4 bv = *reinterpret_cast<const float4*>(Bias + wv * 32 + q * 8 + lhi * 4);
            #pragma unroll
            for (int pt = 0; pt < 4; ++pt) {
                acc[pt][q * 4 + 0] = bv.x; acc[pt][q * 4 + 1] = bv.y;
                acc[pt][q * 4 + 2] = bv.z; acc[pt][q * 4 + 3] = bv.w;
            }
        }
    };

    auto epilogue = [&]() {           // LeakyReLU -> bf16 -> act LDS
        #pragma unroll
        for (int q = 0; q < 4; ++q) {
            const int oc0 = wv * 32 + q * 8 + lhi * 4;
            #pragma unroll
            for (int pt = 0; pt < 4; ++pt) {
                float x[4];
                #pragma unroll
                for (int j = 0; j < 4; ++j) {
                    const float v = acc[pt][q * 4 + j];
                    x[j] = fmaxf(v, 0.2f * v);
                }
                u32x2 wo;
                wo.x = bfpair(x[0], x[1]);
                wo.y = bfpair(x[2], x[3]);
                *reinterpret_cast<u32x2*>(lds + act_off(pt * 32 + l31, oc0 * 2)) = wo;
            }
        }
    };

    auto proc = [&](const u32x4& w, int chunk) {      // 4 ds_read + 4 MFMA for one k-chunk
        const u32 cb = (u32)(chunk * 32 + lhi * 16) ^ swz;
        s16x8 af[4];
        #pragma unroll
        for (int pt = 0; pt < 4; ++pt)
            af[pt] = *reinterpret_cast<const s16x8*>(lds + abase[pt] + cb);
        const s16x8 a = __builtin_bit_cast(s16x8, w);
        __builtin_amdgcn_s_setprio(1);
        #pragma unroll
        for (int pt = 0; pt < 4; ++pt)
            acc[pt] = __builtin_amdgcn_mfma_f32_32x32x16_bf16(a, af[pt], acc[pt], 0, 0, 0);
        __builtin_amdgcn_s_setprio(0);
    };

    // one layer; logical chunk kk -> physical (kk+offc)&maskc; tail prefetches next layer
    // chunks (0..3 + offn)&maskn so each wave starts layer L+1 at its own rotation.
    auto run_layer = [&](int KK, int offc, int offn, int maskn,
                         const char* cur, const char* nxt, const float* Bias) {
        const int maskc = KK - 1;
        init_acc(Bias);
        __syncthreads();              // prior act writes visible
        #pragma unroll 4
        for (int kk = 0; kk < KK; kk += 4) {
            proc(wr0, (kk + 0 + offc) & maskc);
            wr0 = (kk + 4 < KK) ? ldfrag(cur, (kk + 4 + offc) & maskc)
                                : ldfrag(nxt, (0 + offn) & maskn);
            proc(wr1, (kk + 1 + offc) & maskc);
            wr1 = (kk + 5 < KK) ? ldfrag(cur, (kk + 5 + offc) & maskc)
                                : ldfrag(nxt, (1 + offn) & maskn);
            proc(wr2, (kk + 2 + offc) & maskc);
            wr2 = (kk + 6 < KK) ? ldfrag(cur, (kk + 6 + offc) & maskc)
                                : ldfrag(nxt, (2 + offn) & maskn);
            proc(wr3, (kk + 3 + offc) & maskc);
            wr3 = (kk + 7 < KK) ? ldfrag(cur, (kk + 7 + offc) & maskc)
                                : ldfrag(nxt, (3 + offn) & maskn);
        }
        __syncthreads();              // all act reads done before overwrite
        epilogue();
    };

    run_layer(4,  off4,  off16, 15, b0p, b1p, b0);
    run_layer(16, off16, off16, 15, b1p, b2p, b1);
    run_layer(16, off16, off16, 15, b2p, b3p, b2);
    run_layer(16, off16, off16, 15, b3p, b4p, b3);
    run_layer(16, off16, off16, 15, b4p, b4p, b4);    // nxt=self: harmless reload

    // ---------------- head: waves 0..3 -> px wv*32..+32 (own loads; 16KB, L2-hot) ----------------
    __syncthreads();
    if (wv < 4) {
        f32x16 a;
        #pragma unroll
        for (int r = 0; r < 16; ++r) a[r] = 0.0f;
        const u32 hrow = (u32)((wv * 32 + l31) << 9);
        #pragma unroll 4
        for (int kk = 0; kk < 16; ++kk) {
            const u32x4 wh = *reinterpret_cast<const u32x4*>(bHp + (size_t)kk * 1024 + (size_t)lane * 16);
            const u32 cb = (u32)(kk * 32 + lhi * 16) ^ swz;
            const s16x8 af = *reinterpret_cast<const s16x8*>(lds + hrow + cb);
            a = __builtin_amdgcn_mfma_f32_32x32x16_bf16(__builtin_bit_cast(s16x8, wh), af, a, 0, 0, 0);
        }
        if (lhi == 0) {
            const int p = pix0 + wv * 32 + l31;
            out[p * 3 + 0] = a[0] + bl[0];
            out[p * 3 + 1] = a[1] + bl[1];
            out[p * 3 + 2] = a[2] + bl[2];
        }
    }
}

// =================== fallback (r2-style, used only if ws too small) ===================
extern "C" __global__ __launch_bounds__(512, 2)
void loe_fused_fb(const float* __restrict__ coords,
                  const float* __restrict__ w0, const float* __restrict__ b0,
                  const float* __restrict__ w1, const float* __restrict__ b1,
                  const float* __restrict__ w2, const float* __restrict__ b2,
                  const float* __restrict__ w3, const float* __restrict__ b3,
                  const float* __restrict__ w4, const float* __restrict__ b4,
                  const float* __restrict__ wl, const float* __restrict__ bl,
                  float* __restrict__ out)
{
    extern __shared__ char lds[];
    const int tid  = threadIdx.x;
    const int lane = tid & 63;
    const int wv   = tid >> 6;
    const int wr   = wv >> 2;
    const int wc   = wv & 3;
    const int l31  = lane & 31;
    const int lhi  = lane >> 5;
    const int bid  = (int)blockIdx.x;
    const int pb   = ((bid & 7) << 7) | (bid >> 3);
    const int pix0 = pb << 8;
    const int scol = tid & 255;
    const int kh   = tid >> 8;

    float st[16];
    auto load_plain = [&](const float* W, int s) {
        const float* src = W + (size_t)(s * 32 + kh * 16) * HD + scol;
        #pragma unroll
        for (int j = 0; j < 16; ++j) st[j] = src[(size_t)j * HD];
    };
    auto load_guard = [&](const float* W, int s) {
        #pragma unroll
        for (int j = 0; j < 16; ++j) {
            const int k = s * 32 + kh * 16 + j;
            st[j] = (k < 54) ? W[k * HD + scol] : 0.0f;
        }
    };
    load_guard(w0, 0);
    {
        const int p = tid >> 1;
        const int h = tid & 1;
        const float2 c2 = reinterpret_cast<const float2*>(coords)[pix0 + p];
        const float cf[2] = {c2.x, c2.y};
        #pragma unroll
        for (int u = 0; u < 32; u += 2) {
            float v[2];
            #pragma unroll
            for (int q = 0; q < 2; ++q) {
                const int c = h * 32 + u + q;
                float val;
                if (c < 2) val = cf[c];
                else if (c - 2 >= 52) val = 0.0f;
                else {
                    const int e = c - 2;
                    const float a = cf[(e >> 1) & 1] * (float)(1 << (e >> 2));
                    val = (e & 1) ? cospif(a) : sinpif(a);
                }
                v[q] = val;
            }
            *reinterpret_cast<u32*>(lds + act_off(p, (h * 32 + u) * 2)) = bfpair(v[0], v[1]);
        }
    }
    f32x16 acc[4][2];
    int g = 0;
    auto epilogue = [&](const float* Bias) {
        #pragma unroll
        for (int ct = 0; ct < 2; ++ct)
            #pragma unroll
            for (int q = 0; q < 4; ++q) {
                const int oc0 = wc * 64 + ct * 32 + q * 8 + lhi * 4;
                const float4 bv = *reinterpret_cast<const float4*>(Bias + oc0);
                const float bj[4] = {bv.x, bv.y, bv.z, bv.w};
                #pragma unroll
                for (int pt = 0; pt < 4; ++pt) {
                    const int p = wr * 128 + pt * 32 + l31;
                    float x[4];
                    #pragma unroll
                    for (int j = 0; j < 4; ++j) {
                        float v = acc[pt][ct][q * 4 + j] + bj[j];
                        x[j] = (v > 0.0f) ? v : 0.2f * v;
                    }
                    u32x2 wv2;
                    wv2.x = bfpair(x[0], x[1]);
                    wv2.y = bfpair(x[2], x[3]);
                    *reinterpret_cast<u32x2*>(lds + act_off(p, oc0 * 2)) = wv2;
                }
            }
    };
    auto run_layer = [&](int S, const float* Wcur, const float* Wnext,
                         const float* Bias, bool guard) {
        #pragma unroll
        for (int pt = 0; pt < 4; ++pt)
            #pragma unroll
            for (int ct = 0; ct < 2; ++ct)
                #pragma unroll
                for (int r = 0; r < 16; ++r) acc[pt][ct][r] = 0.0f;
        for (int s = 0; s < S; ++s) {
            char* wbw = lds + ACT_BYTES + ((g & 1) ? WBUF_BYTES : 0);
            u32x4 pk0, pk1;
            pk0.x = bfpair(st[0], st[1]);   pk0.y = bfpair(st[2], st[3]);
            pk0.z = bfpair(st[4], st[5]);   pk0.w = bfpair(st[6], st[7]);
            pk1.x = bfpair(st[8], st[9]);   pk1.y = bfpair(st[10], st[11]);
            pk1.z = bfpair(st[12], st[13]); pk1.w = bfpair(st[14], st[15]);
            *reinterpret_cast<u32x4*>(wbw + w_off32(scol, kh * 32))      = pk0;
            *reinterpret_cast<u32x4*>(wbw + w_off32(scol, kh * 32 + 16)) = pk1;
            if (s + 1 < S) { if (guard) load_guard(Wcur, s + 1); else load_plain(Wcur, s + 1); }
            else if (Wnext) load_plain(Wnext, 0);
            __syncthreads();
            #pragma unroll
            for (int kt = 0; kt < 2; ++kt) {
                const int kb = kt * 32 + lhi * 16;
                s16x8 wf[2], af[4];
                #pragma unroll
                for (int ct = 0; ct < 2; ++ct)
                    wf[ct] = *reinterpret_cast<const s16x8*>(wbw + w_off32(wc * 64 + ct * 32 + l31, kb));
                #pragma unroll
                for (int pt = 0; pt < 4; ++pt)
                    af[pt] = *reinterpret_cast<const s16x8*>(lds + act_off(wr * 128 + pt * 32 + l31, s * 64 + kb));
                #pragma unroll
                for (int pt = 0; pt < 4; ++pt)
                    #pragma unroll
                    for (int ct = 0; ct < 2; ++ct)
                        acc[pt][ct] = __builtin_amdgcn_mfma_f32_32x32x16_bf16(wf[ct], af[pt], acc[pt][ct], 0, 0, 0);
            }
            ++g;
            __syncthreads();
        }
        epilogue(Bias);
        __syncthreads();
    };
    const float* w1t = w1 + (size_t)(pb >> 8) * 65536;
    const float* w2t = w2 + (size_t)(pb >> 6) * 65536;
    const float* w3t = w3 + (size_t)(pb >> 4) * 65536;
    const float* w4t = w4 + (size_t)(pb >> 2) * 65536;
    __syncthreads();
    run_layer(2, w0,  w1t, b0, true);
    run_layer(8, w1t, w2t, b1, false);
    run_layer(8, w2t, w3t, b2, false);
    run_layer(8, w3t, w4t, b3, false);
    run_layer(8, w4t, nullptr, b4, false);
    char* hw = lds + ACT_BYTES;
    #pragma unroll
    for (int rep = 0; rep < 2; ++rep) {
        const int task = rep * 512 + tid;
        const int col  = task & 31;
        const int kg   = task >> 5;
        float v[8];
        #pragma unroll
        for (int j = 0; j < 8; ++j)
            v[j] = (col < 3) ? wl[col * HD + kg * 8 + j] : 0.0f;
        u32x4 pk;
        pk.x = bfpair(v[0], v[1]); pk.y = bfpair(v[2], v[3]);
        pk.z = bfpair(v[4], v[5]); pk.w = bfpair(v[6], v[7]);
        *reinterpret_cast<u32x4*>(hw + col * 512 + ((kg * 16) ^ ((col & 7) << 4))) = pk;
    }
    __syncthreads();
    {
        f32x16 a;
        #pragma unroll
        for (int r = 0; r < 16; ++r) a[r] = 0.0f;
        #pragma unroll
        for (int kt = 0; kt < 16; ++kt) {
            const int kb = kt * 32 + lhi * 16;
            s16x8 wf = *reinterpret_cast<const s16x8*>(hw + l31 * 512 + (kb ^ ((l31 & 7) << 4)));
            s16x8 af = *reinterpret_cast<const s16x8*>(lds + act_off(wv * 32 + l31, kb));
            a = __builtin_amdgcn_mfma_f32_32x32x16_bf16(wf, af, a, 0, 0, 0);
        }
        if (lhi == 0) {
            const int p = pix0 + wv * 32 + l31;
            out[p * 3 + 0] = a[0] + bl[0];
            out[p * 3 + 1] = a[1] + bl[1];
            out[p * 3 + 2] = a[2] + bl[2];
        }
    }
}

extern "C" void kernel_launch(void* const* d_in, const int* in_sizes, int n_in,
                              void* d_out, int out_size, void* d_ws, size_t ws_size,
                              hipStream_t stream) {
    (void)in_sizes; (void)n_in; (void)out_size;
    const float* coords = (const float*)d_in[0];
    const float* w0 = (const float*)d_in[1];  const float* b0 = (const float*)d_in[2];
    const float* w1 = (const float*)d_in[3];  const float* b1 = (const float*)d_in[4];
    const float* w2 = (const float*)d_in[5];  const float* b2 = (const float*)d_in[6];
    const float* w3 = (const float*)d_in[7];  const float* b3 = (const float*)d_in[8];
    const float* w4 = (const float*)d_in[9];  const float* b4 = (const float*)d_in[10];
    const float* wl = (const float*)d_in[11]; const float* bl = (const float*)d_in[12];
    float* out = (float*)d_out;

    if (ws_size >= (size_t)BLOB_TOTAL) {
        (void)hipFuncSetAttribute((const void*)loe_fused_pre,
                                  hipFuncAttributeMaxDynamicSharedMemorySize, ACT_LDS);
        loe_prepass<<<dim3((F_END + 255) / 256), dim3(256), 0, stream>>>(
            w0, w1, w2, w3, w4, wl, (char*)d_ws);
        loe_fused_pre<<<dim3(NBLK), dim3(FTHR), ACT_LDS, stream>>>(
            coords, b0, b1, b2, b3, b4, bl, (const char*)d_ws, out);
    } else {
        (void)hipFuncSetAttribute((const void*)loe_fused_fb,
                                  hipFuncAttributeMaxDynamicSharedMemorySize, FB_LDS);
        loe_fused_fb<<<dim3(NPIX / 256), dim3(512), FB_LDS, stream>>>(
            coords, w0, b0, w1, b1, w2, b2, w3, b3, w4, b4, wl, bl, out);
    }
}

// Round 11
// 176.324 us; speedup vs baseline: 1.2256x; 1.2256x over previous
//
#include <hip/hip_runtime.h>
#include <hip/hip_bf16.h>
#include <stdint.h>

typedef uint32_t u32;
typedef short s16x8 __attribute__((ext_vector_type(8)));
typedef float f32x16 __attribute__((ext_vector_type(16)));
typedef u32 u32x2 __attribute__((ext_vector_type(2)));
typedef u32 u32x4 __attribute__((ext_vector_type(4)));

#define NPIX   262144
#define HD     256

// ---------------- fused geometry (r8 partition) ----------------
// 128 px per block, 512 threads (8 waves, one 32-feature block each),
// act-only LDS = 64 KB -> 2 blocks/CU -> 4 waves/SIMD.
#define FTHR      512
#define PXB       128
#define NBLK      (NPIX / PXB)        // 2048
#define ACT_LDS   65536

// ---------------- weight blob (d_ws): per-lane MFMA A-fragment images ----------------
// hidden tile = [kk 16][fb 8][lane 64] x 16B = 128 KB; frag(lane) holds
// W[k = kk*16 + (lane>>5)*8 + j][f = fb*32 + (lane&31)], j=0..7, bf16.
#define B0_OFF  0u           // w0: [kk 4][fb 8][lane] = 32 KB (K=54 padded to 64)
#define B1_OFF  32768u       // w1: 4 tiles
#define B2_OFF  557056u      // w2: 16 tiles
#define B3_OFF  2654208u     // w3: 64 tiles
#define B4_OFF  11042816u    // w4: 256 tiles
#define BH_OFF  44597248u    // head: [kk 16][lane 64] = 16 KB (3 ch padded to 32)
#define BLOB_TOTAL 44613632u
#define F_W1 2048u
#define F_W2 34816u
#define F_W3 165888u
#define F_W4 690176u
#define F_WH 2787328u
#define F_END 2788352u

// fallback (r2-style) LDS layout
#define ACT_BYTES  131072
#define WBUF_BYTES 16384
#define FB_LDS     (ACT_BYTES + 2 * WBUF_BYTES)

__device__ __forceinline__ u32 bfpair(float a, float b) {   // RTNE pack (bit ops, proven)
    u32 ua = __builtin_bit_cast(u32, a);
    u32 ub = __builtin_bit_cast(u32, b);
    ua = (ua + 0x7FFFu + ((ua >> 16) & 1u)) >> 16;
    ub = (ub + 0x7FFFu + ((ub >> 16) & 1u)) >> 16;
    return ua | (ub << 16);
}
// RTNE pack via official intrinsic (compiler emits packed cvt; same rounding as bfpair)
__device__ __forceinline__ u32 packrn(float a, float b) {
    __hip_bfloat162 h = __float22bfloat162_rn(make_float2(a, b));
    u32 r; __builtin_memcpy(&r, &h, 4);
    return r;
}
// act: row stride 512B; XOR-swizzle byte bits 4-8 by row&31 (bijective, 32-slot spread)
__device__ __forceinline__ u32 act_off(int row, int colByte) {
    return (u32)((row << 9) + (colByte ^ ((row & 31) << 4)));
}
// fallback wbuf: col stride 64B, swizzle bits 4-5 by (col>>1)&3
__device__ __forceinline__ u32 w_off32(int col, int kByte) {
    return (u32)((col << 6) + (kByte ^ (((col >> 1) & 3) << 4)));
}

// =================== pre-pass: f32 weights -> per-lane fragment blob (r6-identical) ===========
extern "C" __global__ __launch_bounds__(256)
void loe_prepass(const float* __restrict__ w0, const float* __restrict__ w1,
                 const float* __restrict__ w2, const float* __restrict__ w3,
                 const float* __restrict__ w4, const float* __restrict__ wl,
                 char* __restrict__ ws)
{
    const u32 f = blockIdx.x * 256 + threadIdx.x;   // one 16B fragment chunk
    if (f >= F_END) return;
    float v[8];
    char* dst;
    if (f < F_W1) {                                   // ---- w0 ----
        const u32 kk = f >> 9, fb = (f >> 6) & 7, lane = f & 63;
        const u32 l31 = lane & 31, lhi = lane >> 5;
        const u32 k0 = kk * 16 + lhi * 8, col = fb * 32 + l31;
        #pragma unroll
        for (int j = 0; j < 8; ++j)
            v[j] = (k0 + j < 54) ? w0[(k0 + j) * HD + col] : 0.0f;
        dst = ws + B0_OFF + (size_t)f * 16;
    } else if (f < F_WH) {                            // ---- hidden layers ----
        const float* W; size_t boff; u32 fl;
        if (f < F_W2)      { W = w1; boff = B1_OFF; fl = f - F_W1; }
        else if (f < F_W3) { W = w2; boff = B2_OFF; fl = f - F_W2; }
        else if (f < F_W4) { W = w3; boff = B3_OFF; fl = f - F_W3; }
        else               { W = w4; boff = B4_OFF; fl = f - F_W4; }
        const u32 t = fl >> 13, c = fl & 8191;
        const u32 kk = c >> 9, fb = (c >> 6) & 7, lane = c & 63;
        const u32 l31 = lane & 31, lhi = lane >> 5;
        const u32 k0 = kk * 16 + lhi * 8, col = fb * 32 + l31;
        const float* src = W + (size_t)t * 65536 + (size_t)k0 * HD + col;
        #pragma unroll
        for (int j = 0; j < 8; ++j) v[j] = src[(size_t)j * HD];
        dst = ws + boff + (size_t)fl * 16;
    } else {                                          // ---- head ----
        const u32 fl = f - F_WH;
        const u32 kk = fl >> 6, lane = fl & 63;
        const u32 l31 = lane & 31, lhi = lane >> 5;
        const u32 k0 = kk * 16 + lhi * 8;
        #pragma unroll
        for (int j = 0; j < 8; ++j)
            v[j] = (l31 < 3) ? wl[l31 * HD + k0 + j] : 0.0f;
        dst = ws + BH_OFF + (size_t)fl * 16;
    }
    u32x4 pk;
    pk.x = bfpair(v[0], v[1]); pk.y = bfpair(v[2], v[3]);
    pk.z = bfpair(v[4], v[5]); pk.w = bfpair(v[6], v[7]);
    *reinterpret_cast<u32x4*>(dst) = pk;
}

// =================== fused MLP: 8 waves, depth-4 W prefetch threaded across layers ============
extern "C" __global__ __launch_bounds__(FTHR, 4)
void loe_fused_pre(const float* __restrict__ coords,
                   const float* __restrict__ b0, const float* __restrict__ b1,
                   const float* __restrict__ b2, const float* __restrict__ b3,
                   const float* __restrict__ b4, const float* __restrict__ bl,
                   const char* __restrict__ blob,
                   float* __restrict__ out)
{
    extern __shared__ char lds[];

    const int tid  = threadIdx.x;
    const int lane = tid & 63;
    const int wv   = tid >> 6;      // wave 0..7 = 32-feature block (head: px group for wv<4)
    const int l31  = lane & 31;
    const int lhi  = lane >> 5;

    const int bid  = (int)blockIdx.x;
    const int pb   = ((bid & 7) << 8) | (bid >> 3);   // bijective XCD swizzle (2048 = 8*256)
    const int pix0 = pb << 7;

    const size_t fragoff = (size_t)wv * 1024 + (size_t)lane * 16;
    auto ldfrag = [&](const char* base, int chunk) -> u32x4 {
        return *reinterpret_cast<const u32x4*>(base + (size_t)chunk * 8192 + fragoff);
    };

    const char* b0p = blob + B0_OFF;
    const char* b1p = blob + B1_OFF + (size_t)(pb >> 9) * 131072;
    const char* b2p = blob + B2_OFF + (size_t)(pb >> 7) * 131072;
    const char* b3p = blob + B3_OFF + (size_t)(pb >> 5) * 131072;
    const char* b4p = blob + B4_OFF + (size_t)(pb >> 3) * 131072;
    const char* bHp = blob + BH_OFF;

    // depth-4 W pipeline registers; layer-0 prologue issued BEFORE the PE trig burst
    u32x4 wr0 = ldfrag(b0p, 0), wr1 = ldfrag(b0p, 1),
          wr2 = ldfrag(b0p, 2), wr3 = ldfrag(b0p, 3);

    // ---------------- positional encoding -> act[128 px][64 cols] ----------------
    {
        const int p = tid >> 2;         // 4 threads per pixel
        const int h = tid & 3;          // 16 cols each
        const float2 c2 = reinterpret_cast<const float2*>(coords)[pix0 + p];
        const float cf[2] = {c2.x, c2.y};
        #pragma unroll
        for (int u = 0; u < 16; u += 2) {
            float v[2];
            #pragma unroll
            for (int q = 0; q < 2; ++q) {
                const int c = h * 16 + u + q;
                float val;
                if (c < 2) val = cf[c];
                else if (c - 2 >= 52) val = 0.0f;
                else {
                    const int e = c - 2;
                    const float a = cf[(e >> 1) & 1] * (float)(1 << (e >> 2));  // exact pow2 scale
                    val = (e & 1) ? cospif(a) : sinpif(a);     // proven path (r1-r4,r6-r8)
                }
                v[q] = val;
            }
            *reinterpret_cast<u32*>(lds + act_off(p, (h * 16 + u) * 2)) = packrn(v[0], v[1]);
        }
    }

    f32x16 acc[4];                    // acc[px-block]; D row=feature(32 of wave), col=px
    const u32 swz = (u32)(l31 << 4);
    u32 abase[4];
    #pragma unroll
    for (int pt = 0; pt < 4; ++pt) abase[pt] = (u32)((pt * 32 + l31) << 9);

    auto init_acc = [&](const float* Bias) {
        #pragma unroll
        for (int q = 0; q < 4; ++q) {
            const float4 bv = *reinterpret_cast<const float4*>(Bias + wv * 32 + q * 8 + lhi * 4);
            #pragma unroll
            for (int pt = 0; pt < 4; ++pt) {
                acc[pt][q * 4 + 0] = bv.x; acc[pt][q * 4 + 1] = bv.y;
                acc[pt][q * 4 + 2] = bv.z; acc[pt][q * 4 + 3] = bv.w;
            }
        }
    };

    auto epilogue = [&]() {           // LeakyReLU -> bf16 (packed cvt) -> act LDS
        #pragma unroll
        for (int q = 0; q < 4; ++q) {
            const int oc0 = wv * 32 + q * 8 + lhi * 4;
            #pragma unroll
            for (int pt = 0; pt < 4; ++pt) {
                float x[4];
                #pragma unroll
                for (int j = 0; j < 4; ++j) {
                    const float v = acc[pt][q * 4 + j];
                    x[j] = fmaxf(v, 0.2f * v);
                }
                u32x2 wo;
                wo.x = packrn(x[0], x[1]);
                wo.y = packrn(x[2], x[3]);
                *reinterpret_cast<u32x2*>(lds + act_off(pt * 32 + l31, oc0 * 2)) = wo;
            }
        }
    };

    auto proc = [&](const u32x4& w, int chunk) {      // 4 ds_read + 4 MFMA for one k-chunk
        const u32 cb = (u32)(chunk * 32 + lhi * 16) ^ swz;
        s16x8 af[4];
        #pragma unroll
        for (int pt = 0; pt < 4; ++pt)
            af[pt] = *reinterpret_cast<const s16x8*>(lds + abase[pt] + cb);
        const s16x8 a = __builtin_bit_cast(s16x8, w);
        #pragma unroll
        for (int pt = 0; pt < 4; ++pt)
            acc[pt] = __builtin_amdgcn_mfma_f32_32x32x16_bf16(a, af[pt], acc[pt], 0, 0, 0);
    };

    // one layer; last chunk-group issues next layer's chunks 0..3 into the W regs
    auto run_layer = [&](int KK, const char* cur, const char* nxt, const float* Bias) {
        init_acc(Bias);
        __syncthreads();              // prior act writes visible
        #pragma unroll
        for (int kk = 0; kk < KK; kk += 4) {
            proc(wr0, kk + 0); wr0 = (kk + 4 < KK) ? ldfrag(cur, kk + 4) : ldfrag(nxt, 0);
            proc(wr1, kk + 1); wr1 = (kk + 5 < KK) ? ldfrag(cur, kk + 5) : ldfrag(nxt, 1);
            proc(wr2, kk + 2); wr2 = (kk + 6 < KK) ? ldfrag(cur, kk + 6) : ldfrag(nxt, 2);
            proc(wr3, kk + 3); wr3 = (kk + 7 < KK) ? ldfrag(cur, kk + 7) : ldfrag(nxt, 3);
        }
        __syncthreads();              // all act reads done before overwrite
        epilogue();
    };

    run_layer(4,  b0p, b1p, b0);
    run_layer(16, b1p, b2p, b1);
    run_layer(16, b2p, b3p, b2);
    run_layer(16, b3p, b4p, b3);
    run_layer(16, b4p, b4p, b4);      // nxt=self: harmless reload keeps code uniform

    // ---------------- head: waves 0..3 -> px wv*32..+32 (own loads; 16KB, L2-hot) ----------------
    __syncthreads();
    if (wv < 4) {
        f32x16 a;
        #pragma unroll
        for (int r = 0; r < 16; ++r) a[r] = 0.0f;
        const u32 hrow = (u32)((wv * 32 + l31) << 9);
        #pragma unroll 4
        for (int kk = 0; kk < 16; ++kk) {
            const u32x4 wh = *reinterpret_cast<const u32x4*>(bHp + (size_t)kk * 1024 + (size_t)lane * 16);
            const u32 cb = (u32)(kk * 32 + lhi * 16) ^ swz;
            const s16x8 af = *reinterpret_cast<const s16x8*>(lds + hrow + cb);
            a = __builtin_amdgcn_mfma_f32_32x32x16_bf16(__builtin_bit_cast(s16x8, wh), af, a, 0, 0, 0);
        }
        if (lhi == 0) {
            const int p = pix0 + wv * 32 + l31;
            out[p * 3 + 0] = a[0] + bl[0];
            out[p * 3 + 1] = a[1] + bl[1];
            out[p * 3 + 2] = a[2] + bl[2];
        }
    }
}

// =================== fallback (r2-style, used only if ws too small) ===================
extern "C" __global__ __launch_bounds__(512, 2)
void loe_fused_fb(const float* __restrict__ coords,
                  const float* __restrict__ w0, const float* __restrict__ b0,
                  const float* __restrict__ w1, const float* __restrict__ b1,
                  const float* __restrict__ w2, const float* __restrict__ b2,
                  const float* __restrict__ w3, const float* __restrict__ b3,
                  const float* __restrict__ w4, const float* __restrict__ b4,
                  const float* __restrict__ wl, const float* __restrict__ bl,
                  float* __restrict__ out)
{
    extern __shared__ char lds[];
    const int tid  = threadIdx.x;
    const int lane = tid & 63;
    const int wv   = tid >> 6;
    const int wr   = wv >> 2;
    const int wc   = wv & 3;
    const int l31  = lane & 31;
    const int lhi  = lane >> 5;
    const int bid  = (int)blockIdx.x;
    const int pb   = ((bid & 7) << 7) | (bid >> 3);
    const int pix0 = pb << 8;
    const int scol = tid & 255;
    const int kh   = tid >> 8;

    float st[16];
    auto load_plain = [&](const float* W, int s) {
        const float* src = W + (size_t)(s * 32 + kh * 16) * HD + scol;
        #pragma unroll
        for (int j = 0; j < 16; ++j) st[j] = src[(size_t)j * HD];
    };
    auto load_guard = [&](const float* W, int s) {
        #pragma unroll
        for (int j = 0; j < 16; ++j) {
            const int k = s * 32 + kh * 16 + j;
            st[j] = (k < 54) ? W[k * HD + scol] : 0.0f;
        }
    };
    load_guard(w0, 0);
    {
        const int p = tid >> 1;
        const int h = tid & 1;
        const float2 c2 = reinterpret_cast<const float2*>(coords)[pix0 + p];
        const float cf[2] = {c2.x, c2.y};
        #pragma unroll
        for (int u = 0; u < 32; u += 2) {
            float v[2];
            #pragma unroll
            for (int q = 0; q < 2; ++q) {
                const int c = h * 32 + u + q;
                float val;
                if (c < 2) val = cf[c];
                else if (c - 2 >= 52) val = 0.0f;
                else {
                    const int e = c - 2;
                    const float a = cf[(e >> 1) & 1] * (float)(1 << (e >> 2));
                    val = (e & 1) ? cospif(a) : sinpif(a);
                }
                v[q] = val;
            }
            *reinterpret_cast<u32*>(lds + act_off(p, (h * 32 + u) * 2)) = bfpair(v[0], v[1]);
        }
    }
    f32x16 acc[4][2];
    int g = 0;
    auto epilogue = [&](const float* Bias) {
        #pragma unroll
        for (int ct = 0; ct < 2; ++ct)
            #pragma unroll
            for (int q = 0; q < 4; ++q) {
                const int oc0 = wc * 64 + ct * 32 + q * 8 + lhi * 4;
                const float4 bv = *reinterpret_cast<const float4*>(Bias + oc0);
                const float bj[4] = {bv.x, bv.y, bv.z, bv.w};
                #pragma unroll
                for (int pt = 0; pt < 4; ++pt) {
                    const int p = wr * 128 + pt * 32 + l31;
                    float x[4];
                    #pragma unroll
                    for (int j = 0; j < 4; ++j) {
                        float v = acc[pt][ct][q * 4 + j] + bj[j];
                        x[j] = (v > 0.0f) ? v : 0.2f * v;
                    }
                    u32x2 wv2;
                    wv2.x = bfpair(x[0], x[1]);
                    wv2.y = bfpair(x[2], x[3]);
                    *reinterpret_cast<u32x2*>(lds + act_off(p, oc0 * 2)) = wv2;
                }
            }
    };
    auto run_layer = [&](int S, const float* Wcur, const float* Wnext,
                         const float* Bias, bool guard) {
        #pragma unroll
        for (int pt = 0; pt < 4; ++pt)
            #pragma unroll
            for (int ct = 0; ct < 2; ++ct)
                #pragma unroll
                for (int r = 0; r < 16; ++r) acc[pt][ct][r] = 0.0f;
        for (int s = 0; s < S; ++s) {
            char* wbw = lds + ACT_BYTES + ((g & 1) ? WBUF_BYTES : 0);
            u32x4 pk0, pk1;
            pk0.x = bfpair(st[0], st[1]);   pk0.y = bfpair(st[2], st[3]);
            pk0.z = bfpair(st[4], st[5]);   pk0.w = bfpair(st[6], st[7]);
            pk1.x = bfpair(st[8], st[9]);   pk1.y = bfpair(st[10], st[11]);
            pk1.z = bfpair(st[12], st[13]); pk1.w = bfpair(st[14], st[15]);
            *reinterpret_cast<u32x4*>(wbw + w_off32(scol, kh * 32))      = pk0;
            *reinterpret_cast<u32x4*>(wbw + w_off32(scol, kh * 32 + 16)) = pk1;
            if (s + 1 < S) { if (guard) load_guard(Wcur, s + 1); else load_plain(Wcur, s + 1); }
            else if (Wnext) load_plain(Wnext, 0);
            __syncthreads();
            #pragma unroll
            for (int kt = 0; kt < 2; ++kt) {
                const int kb = kt * 32 + lhi * 16;
                s16x8 wf[2], af[4];
                #pragma unroll
                for (int ct = 0; ct < 2; ++ct)
                    wf[ct] = *reinterpret_cast<const s16x8*>(wbw + w_off32(wc * 64 + ct * 32 + l31, kb));
                #pragma unroll
                for (int pt = 0; pt < 4; ++pt)
                    af[pt] = *reinterpret_cast<const s16x8*>(lds + act_off(wr * 128 + pt * 32 + l31, s * 64 + kb));
                #pragma unroll
                for (int pt = 0; pt < 4; ++pt)
                    #pragma unroll
                    for (int ct = 0; ct < 2; ++ct)
                        acc[pt][ct] = __builtin_amdgcn_mfma_f32_32x32x16_bf16(wf[ct], af[pt], acc[pt][ct], 0, 0, 0);
            }
            ++g;
            __syncthreads();
        }
        epilogue(Bias);
        __syncthreads();
    };
    const float* w1t = w1 + (size_t)(pb >> 8) * 65536;
    const float* w2t = w2 + (size_t)(pb >> 6) * 65536;
    const float* w3t = w3 + (size_t)(pb >> 4) * 65536;
    const float* w4t = w4 + (size_t)(pb >> 2) * 65536;
    __syncthreads();
    run_layer(2, w0,  w1t, b0, true);
    run_layer(8, w1t, w2t, b1, false);
    run_layer(8, w2t, w3t, b2, false);
    run_layer(8, w3t, w4t, b3, false);
    run_layer(8, w4t, nullptr, b4, false);
    char* hw = lds + ACT_BYTES;
    #pragma unroll
    for (int rep = 0; rep < 2; ++rep) {
        const int task = rep * 512 + tid;
        const int col  = task & 31;
        const int kg   = task >> 5;
        float v[8];
        #pragma unroll
        for (int j = 0; j < 8; ++j)
            v[j] = (col < 3) ? wl[col * HD + kg * 8 + j] : 0.0f;
        u32x4 pk;
        pk.x = bfpair(v[0], v[1]); pk.y = bfpair(v[2], v[3]);
        pk.z = bfpair(v[4], v[5]); pk.w = bfpair(v[6], v[7]);
        *reinterpret_cast<u32x4*>(hw + col * 512 + ((kg * 16) ^ ((col & 7) << 4))) = pk;
    }
    __syncthreads();
    {
        f32x16 a;
        #pragma unroll
        for (int r = 0; r < 16; ++r) a[r] = 0.0f;
        #pragma unroll
        for (int kt = 0; kt < 16; ++kt) {
            const int kb = kt * 32 + lhi * 16;
            s16x8 wf = *reinterpret_cast<const s16x8*>(hw + l31 * 512 + (kb ^ ((l31 & 7) << 4)));
            s16x8 af = *reinterpret_cast<const s16x8*>(lds + act_off(wv * 32 + l31, kb));
            a = __builtin_amdgcn_mfma_f32_32x32x16_bf16(wf, af, a, 0, 0, 0);
        }
        if (lhi == 0) {
            const int p = pix0 + wv * 32 + l31;
            out[p * 3 + 0] = a[0] + bl[0];
            out[p * 3 + 1] = a[1] + bl[1];
            out[p * 3 + 2] = a[2] + bl[2];
        }
    }
}

extern "C" void kernel_launch(void* const* d_in, const int* in_sizes, int n_in,
                              void* d_out, int out_size, void* d_ws, size_t ws_size,
                              hipStream_t stream) {
    (void)in_sizes; (void)n_in; (void)out_size;
    const float* coords = (const float*)d_in[0];
    const float* w0 = (const float*)d_in[1];  const float* b0 = (const float*)d_in[2];
    const float* w1 = (const float*)d_in[3];  const float* b1 = (const float*)d_in[4];
    const float* w2 = (const float*)d_in[5];  const float* b2 = (const float*)d_in[6];
    const float* w3 = (const float*)d_in[7];  const float* b3 = (const float*)d_in[8];
    const float* w4 = (const float*)d_in[9];  const float* b4 = (const float*)d_in[10];
    const float* wl = (const float*)d_in[11]; const float* bl = (const float*)d_in[12];
    float* out = (float*)d_out;

    if (ws_size >= (size_t)BLOB_TOTAL) {
        (void)hipFuncSetAttribute((const void*)loe_fused_pre,
                                  hipFuncAttributeMaxDynamicSharedMemorySize, ACT_LDS);
        loe_prepass<<<dim3((F_END + 255) / 256), dim3(256), 0, stream>>>(
            w0, w1, w2, w3, w4, wl, (char*)d_ws);
        loe_fused_pre<<<dim3(NBLK), dim3(FTHR), ACT_LDS, stream>>>(
            coords, b0, b1, b2, b3, b4, bl, (const char*)d_ws, out);
    } else {
        (void)hipFuncSetAttribute((const void*)loe_fused_fb,
                                  hipFuncAttributeMaxDynamicSharedMemorySize, FB_LDS);
        loe_fused_fb<<<dim3(NPIX / 256), dim3(512), FB_LDS, stream>>>(
            coords, w0, b0, w1, b1, w2, b2, w3, b3, w4, b4, wl, bl, out);
    }
}